// Round 1
// baseline (127.252 us; speedup 1.0000x reference)
//
#include <hip/hip_runtime.h>

#define N_ATOMS  4096
#define N_RBF    16
#define N_HIDDEN 64
#define NBLOCKS  512
#define WAVES_PER_BLOCK 4

__global__ void zero_out_kernel(float* __restrict__ out) {
    if (threadIdx.x == 0 && blockIdx.x == 0) out[0] = 0.0f;
}

__global__ __launch_bounds__(256) void fused_sr_kernel(
    const float* __restrict__ pos,   // (N,3)
    const float* __restrict__ W1,    // (16,64)
    const float* __restrict__ b1,    // (64,)
    const float* __restrict__ W2,    // (64,64)
    const float* __restrict__ b2,    // (64,)
    const float* __restrict__ W3,    // (64,1)
    const float* __restrict__ b3,    // (1,)
    float* __restrict__ out)         // scalar
{
    __shared__ float sx[N_ATOMS];
    __shared__ float sy[N_ATOMS];
    __shared__ float sz[N_ATOMS];
    __shared__ __align__(16) float h1buf[WAVES_PER_BLOCK][N_HIDDEN];

    const int tid = threadIdx.x;

    // Stage positions SoA into LDS (48 KB); L2-resident source, once per block.
    for (int idx = tid; idx < N_ATOMS; idx += 256) {
        sx[idx] = pos[idx * 3 + 0];
        sy[idx] = pos[idx * 3 + 1];
        sz[idx] = pos[idx * 3 + 2];
    }
    __syncthreads();

    const int lane = tid & 63;
    const int wib  = tid >> 6;                       // wave index in block
    const int gw   = blockIdx.x * WAVES_PER_BLOCK + wib;
    const int NW   = NBLOCKS * WAVES_PER_BLOCK;      // 2048 waves

    // Each wave owns atoms i = gw, gw+NW, ...
    for (int i = gw; i < N_ATOMS; i += NW) {
        const float xi = sx[i], yi = sy[i], zi = sz[i];  // wave-uniform broadcast

        float f[N_RBF];
        #pragma unroll
        for (int k = 0; k < N_RBF; ++k) f[k] = 0.0f;

        // 64 iterations: lane handles j = lane, lane+64, ...
        for (int j = lane; j < N_ATOMS; j += 64) {
            const float dx = xi - sx[j];
            const float dy = yi - sy[j];
            const float dz = zi - sz[j];
            const float d2 = fmaf(dx, dx, fmaf(dy, dy, dz * dz));
            if (d2 < 25.0f && d2 > 1e-12f) {        // mask: 1e-6 < d < 5
                const float d  = sqrtf(d2);
                // smooth = 0.5*(1+cos(pi*d/5)); d<5 so no clamp needed
                const float sm = 0.5f * (1.0f + __cosf(0.62831853071795865f * d));
                #pragma unroll
                for (int k = 0; k < N_RBF; ++k) {
                    // centers 0.5 + 0.3k; 1/(2*eta^2) = 20.48 exactly
                    const float t = d - (0.5f + 0.3f * (float)k);
                    f[k] += sm * __expf(-20.48f * t * t);
                }
            }
        }

        // Butterfly allreduce of the 16 feature partials across the wave.
        #pragma unroll
        for (int k = 0; k < N_RBF; ++k) {
            #pragma unroll
            for (int off = 32; off > 0; off >>= 1)
                f[k] += __shfl_xor(f[k], off, 64);
        }

        // ---- MLP: lane h <-> hidden unit h ----
        // Layer 1: a1 = b1[h] + sum_k f[k] * W1[k][h]
        float a1 = b1[lane];
        #pragma unroll
        for (int k = 0; k < N_RBF; ++k)
            a1 = fmaf(f[k], W1[k * N_HIDDEN + lane], a1);
        const float h1 = a1 / (1.0f + __expf(-a1));   // silu

        // Exchange h1 across the wave via per-wave LDS buffer (broadcast reads).
        h1buf[wib][lane] = h1;
        // Same-wave LDS write->read: ordered by lgkmcnt the compiler inserts
        // for the dependence through h1buf (no __syncthreads needed).
        float a2 = b2[lane];
        #pragma unroll
        for (int k = 0; k < N_HIDDEN; k += 4) {
            const float4 hv = *reinterpret_cast<const float4*>(&h1buf[wib][k]);
            a2 = fmaf(hv.x, W2[(k + 0) * N_HIDDEN + lane], a2);
            a2 = fmaf(hv.y, W2[(k + 1) * N_HIDDEN + lane], a2);
            a2 = fmaf(hv.z, W2[(k + 2) * N_HIDDEN + lane], a2);
            a2 = fmaf(hv.w, W2[(k + 3) * N_HIDDEN + lane], a2);
        }
        const float h2 = a2 / (1.0f + __expf(-a2));   // silu

        // Layer 3 + per-atom bias, wave-reduce, one atomic per atom.
        float contrib = h2 * W3[lane];
        #pragma unroll
        for (int off = 32; off > 0; off >>= 1)
            contrib += __shfl_xor(contrib, off, 64);
        if (lane == 0) atomicAdd(out, contrib + b3[0]);
    }
}

extern "C" void kernel_launch(void* const* d_in, const int* in_sizes, int n_in,
                              void* d_out, int out_size, void* d_ws, size_t ws_size,
                              hipStream_t stream) {
    const float* pos = (const float*)d_in[0];
    const float* W1  = (const float*)d_in[1];
    const float* b1  = (const float*)d_in[2];
    const float* W2  = (const float*)d_in[3];
    const float* b2  = (const float*)d_in[4];
    const float* W3  = (const float*)d_in[5];
    const float* b3  = (const float*)d_in[6];
    float* out = (float*)d_out;

    // d_out is poisoned (0xAA) before every timed replay -> zero it on-stream.
    zero_out_kernel<<<1, 64, 0, stream>>>(out);
    fused_sr_kernel<<<NBLOCKS, 256, 0, stream>>>(pos, W1, b1, W2, b2, W3, b3, out);
}

// Round 2
// 108.777 us; speedup vs baseline: 1.1698x; 1.1698x over previous
//
#include <hip/hip_runtime.h>

#define N_ATOMS  4096
#define N_RBF    16
#define N_HIDDEN 64
#define NBLOCKS  512
#define WPB      4      // waves per block
#define TI       2      // atoms per wave (amortize LDS j-reads)

__global__ void zero_out_kernel(float* __restrict__ out) {
    if (threadIdx.x == 0 && blockIdx.x == 0) out[0] = 0.0f;
}

// Accumulate one pair's RBF contribution into f[0..15].
// d2 = 1e8 sentinel contributes exactly 0 (exp underflows to 0).
__device__ __forceinline__ void accum_rbf(float d2, float (&f)[N_RBF]) {
    const float d  = sqrtf(d2);
    const float sm = 0.5f + 0.5f * __cosf(0.62831853071795865f * d); // 0.5*(1+cos(pi*d/5))
    #pragma unroll
    for (int k = 0; k < N_RBF; ++k) {
        const float t = d - (0.5f + 0.3f * (float)k);   // centers 0.5+0.3k
        f[k] += sm * __expf(-20.48f * t * t);           // 1/(2*eta^2) = 20.48
    }
}

__global__ __launch_bounds__(256) void fused_sr_kernel(
    const float* __restrict__ pos,   // (N,3)
    const float* __restrict__ W1,    // (16,64)
    const float* __restrict__ b1,    // (64,)
    const float* __restrict__ W2,    // (64,64)
    const float* __restrict__ b2,    // (64,)
    const float* __restrict__ W3,    // (64,1)
    const float* __restrict__ b3,    // (1,)
    float* __restrict__ out)         // scalar
{
    __shared__ __align__(16) float4 sp[N_ATOMS];          // 64 KB, xyz + pad
    __shared__ float qd[WPB][TI][128];                    // 4 KB ring queues (d^2)
    __shared__ __align__(16) float h1buf[WPB][N_HIDDEN];  // 1 KB

    const int tid = threadIdx.x;

    // Stage positions as float4 SoA-of-structs into LDS.
    for (int idx = tid; idx < N_ATOMS; idx += 256) {
        sp[idx] = make_float4(pos[idx * 3 + 0], pos[idx * 3 + 1], pos[idx * 3 + 2], 0.0f);
    }
    __syncthreads();

    const int lane = tid & 63;
    const int wib  = tid >> 6;
    const int gw   = blockIdx.x * WPB + wib;     // 0..2047
    const int i0   = gw * TI;                    // this wave owns atoms i0, i0+1

    const float4 pa = sp[i0];
    const float4 pb = sp[i0 + 1];

    float f[TI][N_RBF];
    #pragma unroll
    for (int a = 0; a < TI; ++a)
        #pragma unroll
        for (int k = 0; k < N_RBF; ++k) f[a][k] = 0.0f;

    int base0 = 0, done0 = 0, base1 = 0, done1 = 0;

    // Distance sweep over all j: cheap check + wave compaction into queues.
    for (int j0 = 0; j0 < N_ATOMS; j0 += 64) {
        const float4 pj = sp[j0 + lane];

        // atom A
        {
            const float dx = pa.x - pj.x, dy = pa.y - pj.y, dz = pa.z - pj.z;
            const float d2 = fmaf(dx, dx, fmaf(dy, dy, dz * dz));
            const bool act = (d2 < 25.0f) && (d2 > 1e-12f);
            const unsigned long long m = __ballot(act);
            const int pfx = __builtin_amdgcn_mbcnt_hi((unsigned)(m >> 32),
                             __builtin_amdgcn_mbcnt_lo((unsigned)m, 0u));
            if (act) qd[wib][0][(base0 + pfx) & 127] = d2;
            base0 += (int)__popcll(m);
        }
        // atom B
        {
            const float dx = pb.x - pj.x, dy = pb.y - pj.y, dz = pb.z - pj.z;
            const float d2 = fmaf(dx, dx, fmaf(dy, dy, dz * dz));
            const bool act = (d2 < 25.0f) && (d2 > 1e-12f);
            const unsigned long long m = __ballot(act);
            const int pfx = __builtin_amdgcn_mbcnt_hi((unsigned)(m >> 32),
                             __builtin_amdgcn_mbcnt_lo((unsigned)m, 0u));
            if (act) qd[wib][1][(base1 + pfx) & 127] = d2;
            base1 += (int)__popcll(m);
        }
        // Flush full batches: all 64 lanes do useful RBF work.
        if (base0 - done0 >= 64) {
            const float d2q = qd[wib][0][(done0 + lane) & 127];
            done0 += 64;
            accum_rbf(d2q, f[0]);
        }
        if (base1 - done1 >= 64) {
            const float d2q = qd[wib][1][(done1 + lane) & 127];
            done1 += 64;
            accum_rbf(d2q, f[1]);
        }
    }
    // Tails (sentinel lanes contribute exactly 0).
    {
        const int rem = base0 - done0;
        const float d2q = (lane < rem) ? qd[wib][0][(done0 + lane) & 127] : 1e8f;
        accum_rbf(d2q, f[0]);
    }
    {
        const int rem = base1 - done1;
        const float d2q = (lane < rem) ? qd[wib][1][(done1 + lane) & 127] : 1e8f;
        accum_rbf(d2q, f[1]);
    }

    // ---- per-atom MLP (lane h <-> hidden unit h), 2 atoms unrolled ----
    float energy = 0.0f;
    #pragma unroll
    for (int a = 0; a < TI; ++a) {
        // Butterfly allreduce the 16 feature partials across the wave.
        #pragma unroll
        for (int k = 0; k < N_RBF; ++k) {
            #pragma unroll
            for (int off = 32; off > 0; off >>= 1)
                f[a][k] += __shfl_xor(f[a][k], off, 64);
        }

        float a1 = b1[lane];
        #pragma unroll
        for (int k = 0; k < N_RBF; ++k)
            a1 = fmaf(f[a][k], W1[k * N_HIDDEN + lane], a1);
        const float h1 = a1 / (1.0f + __expf(-a1));   // silu

        h1buf[wib][lane] = h1;   // same-wave LDS exchange (DS ops are in-order)
        float a2 = b2[lane];
        #pragma unroll
        for (int k = 0; k < N_HIDDEN; k += 4) {
            const float4 hv = *reinterpret_cast<const float4*>(&h1buf[wib][k]);
            a2 = fmaf(hv.x, W2[(k + 0) * N_HIDDEN + lane], a2);
            a2 = fmaf(hv.y, W2[(k + 1) * N_HIDDEN + lane], a2);
            a2 = fmaf(hv.z, W2[(k + 2) * N_HIDDEN + lane], a2);
            a2 = fmaf(hv.w, W2[(k + 3) * N_HIDDEN + lane], a2);
        }
        const float h2 = a2 / (1.0f + __expf(-a2));   // silu

        energy += h2 * W3[lane];
    }

    // One reduce + one atomic per wave (covers both atoms).
    #pragma unroll
    for (int off = 32; off > 0; off >>= 1)
        energy += __shfl_xor(energy, off, 64);
    if (lane == 0) atomicAdd(out, energy + 2.0f * b3[0]);
}

extern "C" void kernel_launch(void* const* d_in, const int* in_sizes, int n_in,
                              void* d_out, int out_size, void* d_ws, size_t ws_size,
                              hipStream_t stream) {
    const float* pos = (const float*)d_in[0];
    const float* W1  = (const float*)d_in[1];
    const float* b1  = (const float*)d_in[2];
    const float* W2  = (const float*)d_in[3];
    const float* b2  = (const float*)d_in[4];
    const float* W3  = (const float*)d_in[5];
    const float* b3  = (const float*)d_in[6];
    float* out = (float*)d_out;

    zero_out_kernel<<<1, 64, 0, stream>>>(out);
    fused_sr_kernel<<<NBLOCKS, 256, 0, stream>>>(pos, W1, b1, W2, b2, W3, b3, out);
}

// Round 3
// 82.888 us; speedup vs baseline: 1.5352x; 1.3123x over previous
//
#include <hip/hip_runtime.h>

#define N_ATOMS  4096
#define N_RBF    16
#define N_HIDDEN 64
#define NBLOCKS  512
#define NTHREADS 512
#define WPB      8        // waves per block, 1 atom per wave
#define QCAP     256      // per-wave candidate queue (max neighbors ~190)

__global__ void zero_out_kernel(float* __restrict__ out) {
    if (threadIdx.x == 0 && blockIdx.x == 0) out[0] = 0.0f;
}

// One pair's RBF contribution into f[0..15]. d2=1e8 sentinel -> exactly 0.
__device__ __forceinline__ void accum_rbf(float d2, float (&f)[N_RBF]) {
    const float d  = sqrtf(d2);
    const float sm = 0.5f + 0.5f * __cosf(0.62831853071795865f * d); // 0.5*(1+cos(pi*d/5))
    #pragma unroll
    for (int k = 0; k < N_RBF; ++k) {
        const float t = d - (0.5f + 0.3f * (float)k);   // centers 0.5+0.3k
        f[k] += sm * __expf(-20.48f * t * t);           // 1/(2*eta^2) = 20.48
    }
}

__global__ __launch_bounds__(NTHREADS, 4) void fused_sr_kernel(
    const float* __restrict__ pos,   // (N,3)
    const float* __restrict__ W1,    // (16,64)
    const float* __restrict__ b1,    // (64,)
    const float* __restrict__ W2,    // (64,64)
    const float* __restrict__ b2,    // (64,)
    const float* __restrict__ W3,    // (64,1)
    const float* __restrict__ b3,    // (1,)
    float* __restrict__ out)         // scalar
{
    __shared__ float sx[N_ATOMS];                         // 16 KB
    __shared__ float sy[N_ATOMS];                         // 16 KB
    __shared__ float sz[N_ATOMS];                         // 16 KB
    __shared__ float qd[WPB][QCAP];                       // 8 KB d^2 queues
    __shared__ __align__(16) float h1buf[WPB][N_HIDDEN];  // 2 KB
    __shared__ float ered[WPB];

    const int tid = threadIdx.x;

    for (int idx = tid; idx < N_ATOMS; idx += NTHREADS) {
        sx[idx] = pos[idx * 3 + 0];
        sy[idx] = pos[idx * 3 + 1];
        sz[idx] = pos[idx * 3 + 2];
    }
    __syncthreads();

    const int lane = tid & 63;
    const int wib  = tid >> 6;
    const int i    = blockIdx.x * WPB + wib;   // this wave's atom

    const float xi = sx[i], yi = sy[i], zi = sz[i];  // wave-uniform

    // ---- branch-free compaction sweep over all j ----
    int cnt = 0;
    #pragma unroll 4
    for (int j0 = 0; j0 < N_ATOMS; j0 += 64) {
        const int j = j0 + lane;
        const float dx = xi - sx[j];
        const float dy = yi - sy[j];
        const float dz = zi - sz[j];
        const float d2 = fmaf(dx, dx, fmaf(dy, dy, dz * dz));
        const bool act = (d2 < 25.0f) && (d2 > 1e-12f);  // 1e-6 < d < 5
        const unsigned long long m = __ballot(act);
        const int pfx = __builtin_amdgcn_mbcnt_hi((unsigned)(m >> 32),
                         __builtin_amdgcn_mbcnt_lo((unsigned)m, 0u));
        int widx = cnt + pfx;
        widx = widx < QCAP ? widx : QCAP - 1;            // overflow clamp (safety)
        if (act) qd[wib][widx] = d2;                     // predicated store, no branch
        cnt += (int)__popcll(m);
    }

    // ---- drain: full-lane RBF evaluation ----
    float f[N_RBF];
    #pragma unroll
    for (int k = 0; k < N_RBF; ++k) f[k] = 0.0f;
    for (int b = 0; b < cnt; b += 64) {
        const int q = b + lane;
        const float d2q = (q < cnt) ? qd[wib][q] : 1e8f;
        accum_rbf(d2q, f);
    }

    // ---- butterfly allreduce of 16 feature partials ----
    #pragma unroll
    for (int k = 0; k < N_RBF; ++k) {
        #pragma unroll
        for (int off = 32; off > 0; off >>= 1)
            f[k] += __shfl_xor(f[k], off, 64);
    }

    // ---- MLP: lane h <-> hidden unit h ----
    float a1 = b1[lane];
    #pragma unroll
    for (int k = 0; k < N_RBF; ++k)
        a1 = fmaf(f[k], W1[k * N_HIDDEN + lane], a1);
    const float h1 = a1 / (1.0f + __expf(-a1));   // silu

    h1buf[wib][lane] = h1;   // same-wave LDS exchange (DS ops in-order)
    float a2 = b2[lane];
    #pragma unroll
    for (int k = 0; k < N_HIDDEN; k += 4) {
        const float4 hv = *reinterpret_cast<const float4*>(&h1buf[wib][k]);
        a2 = fmaf(hv.x, W2[(k + 0) * N_HIDDEN + lane], a2);
        a2 = fmaf(hv.y, W2[(k + 1) * N_HIDDEN + lane], a2);
        a2 = fmaf(hv.z, W2[(k + 2) * N_HIDDEN + lane], a2);
        a2 = fmaf(hv.w, W2[(k + 3) * N_HIDDEN + lane], a2);
    }
    const float h2 = a2 / (1.0f + __expf(-a2));   // silu

    // ---- energy: wave reduce -> block reduce -> one atomic per block ----
    float energy = h2 * W3[lane];
    #pragma unroll
    for (int off = 32; off > 0; off >>= 1)
        energy += __shfl_xor(energy, off, 64);
    if (lane == 0) ered[wib] = energy;
    __syncthreads();
    if (tid == 0) {
        float e = 0.0f;
        #pragma unroll
        for (int w = 0; w < WPB; ++w) e += ered[w];
        atomicAdd(out, e + (float)WPB * b3[0]);
    }
}

extern "C" void kernel_launch(void* const* d_in, const int* in_sizes, int n_in,
                              void* d_out, int out_size, void* d_ws, size_t ws_size,
                              hipStream_t stream) {
    const float* pos = (const float*)d_in[0];
    const float* W1  = (const float*)d_in[1];
    const float* b1  = (const float*)d_in[2];
    const float* W2  = (const float*)d_in[3];
    const float* b2  = (const float*)d_in[4];
    const float* W3  = (const float*)d_in[5];
    const float* b3  = (const float*)d_in[6];
    float* out = (float*)d_out;

    zero_out_kernel<<<1, 64, 0, stream>>>(out);
    fused_sr_kernel<<<NBLOCKS, NTHREADS, 0, stream>>>(pos, W1, b1, W2, b2, W3, b3, out);
}